// Round 1
// 401.015 us; speedup vs baseline: 1.0859x; 1.0859x over previous
//
#include <hip/hip_runtime.h>

// Gather3d sparse-mode constants (from reference)
#define C_DIM 128
#define T_DIM 16
#define H_DIM 128
#define W_DIM 128
#define PAD_T 2
#define TT (T_DIM + PAD_T)           // 18 output planes per (n,c)

// LDS plane layout: row stride 144 floats.
// 144 % 32 == 16 -> a wave's 4x16 (row x col) read footprint hits each bank
// exactly twice (2-way aliasing is free on CDNA4, m136). 128*144*4 = 73,728 B
// -> 2 workgroups / CU (147 KB of the 160 KB LDS pool).
#define S_LDS 144
#define PLANE_F (H_DIM * S_LDS)      // 18432 floats

typedef float f4 __attribute__((ext_vector_type(4), aligned(16)));

__global__ __launch_bounds__(256, 2) void gather3d_plane(
    const float* __restrict__ x,          // [C, T, H, W]
    const int*   __restrict__ active_idx, // [N, 2]
    float*       __restrict__ out,        // [N, C, TT, 16, 16]
    int N)
{
    __shared__ float plane[PLANE_F];

    const int c   = blockIdx.x;           // channel
    const int tt  = blockIdx.y;           // output time plane 0..17
    const int tid = threadIdx.x;

    if (tt >= PAD_T) {
        // Stage the full 128x128 plane x[c][tt-2] into LDS.
        // Dense float4 loads: x is read exactly once, fully coalesced,
        // zero cache-line amplification (vs ~2.9x for the random-offset
        // 64B row reads of the previous kernel).
        const float* __restrict__ src =
            x + ((size_t)c * T_DIM + (size_t)(tt - PAD_T)) * (size_t)(H_DIM * W_DIM);
        #pragma unroll
        for (int it = 0; it < (H_DIM * W_DIM) / (256 * 4); ++it) {  // 16 iters
            const int f   = (it * 256 + tid) * 4;   // float index in plane
            const int r   = f >> 7;                 // 0..127
            const int col = f & 127;                // multiple of 4 -> 16B aligned
            *(f4*)(&plane[r * S_LDS + col]) = *(const f4*)(src + f);
        }
    }
    __syncthreads();

    // Each thread owns one (row,col) cell of the 16x16 block and walks all N
    // output blocks. Stores: 64 lanes x 4B = 256B contiguous per wave instr,
    // nontemporal (don't pollute L3 -- we want x to stay resident).
    const int row = tid >> 4;
    const int col = tid & 15;
    float*       op      = out + ((size_t)c * TT + tt) * 256 + tid;
    const size_t ostride = (size_t)C_DIM * TT * 256;   // stride between n's

    if (tt >= PAD_T) {
        const float* pl = plane + row * S_LDS + col;
        #pragma unroll 4
        for (int n = 0; n < N; ++n) {
            // Uniform address across the wave -> compiler scalarizes to
            // s_load (K$/L2 hit); no LDS staging needed for indices.
            const int i0 = active_idx[2 * n];
            const int i1 = active_idx[2 * n + 1];
            __builtin_nontemporal_store(pl[i0 * S_LDS + i1], op);
            op += ostride;
        }
    } else {
        // tt < PAD_T: causal time padding -> zero planes.
        #pragma unroll 4
        for (int n = 0; n < N; ++n) {
            __builtin_nontemporal_store(0.0f, op);
            op += ostride;
        }
    }
}

extern "C" void kernel_launch(void* const* d_in, const int* in_sizes, int n_in,
                              void* d_out, int out_size, void* d_ws, size_t ws_size,
                              hipStream_t stream) {
    const float* x   = (const float*)d_in[0];
    const int*   idx = (const int*)d_in[1];
    float*       out = (float*)d_out;

    const int N = in_sizes[1] / 2;   // 128 active indices

    dim3 grid(C_DIM, TT);            // one workgroup per (c, tt) plane
    gather3d_plane<<<grid, dim3(256), 0, stream>>>(x, idx, out, N);
}